// Round 3
// baseline (145.170 us; speedup 1.0000x reference)
//
#include <hip/hip_runtime.h>

// SKA: per-pixel dynamic depthwise 5x5 conv
// x: [B=8, C=256, H=64, W=64] f32
// w: [B=8, G=8, K2=25, H=64, W=64] f32
// out[b,c,h,w] = sum_k x[b,c,h+k/5-2,w+k%5-2] * w[b,g,k,h,w], g = c/32
//
// Design H (round 10): design G skeleton + conflict fix + occupancy fix.
// Round-9 evidence: ska 50us/dispatch (REGRESSION vs F2's ~40us),
// SQ_LDS_BANK_CONFLICT 5.05M (=14.4 extra clk per ds_read_b128: PITCH=68
// puts 8 lanes on each 16B bank-quad -> ~2.9x the 8-clk floor, m136's 8-way
// cost), Occupancy 18% (LDS 44KB caps 3 blocks/CU; bulk stage->barrier
// phases align with too few peer blocks to hide).
// Fixes:
//  - PITCH=70 + 4x ds_read_b64 inner reads: bank-pair = (3*row+2j+t) mod 16,
//    even rows -> even pairs, odd rows -> odd pairs => uniform 4 lanes/pair
//    = exact b64 floor (the discipline F2 used). Odd rows are 8B-misaligned
//    from 16B so the compiler cannot re-merge float2 pairs into b128.
//  - NCH=4 -> LDS 22.5KB/block, grid 2048, __launch_bounds__(256,6):
//    6 blocks/CU = 24 waves/CU (2x round-9). Stage phase of one block hides
//    under compute of five others.
//  - chunk (now 3 bits) stays in SLOW blockIdx bits: stride-256 partners
//    keep blk%8 -> same XCD -> w re-reads (8x now) hit that XCD's L2; all
//    of w (26MB) fits L3 regardless.
// Weights: row-wise double-buffer (40 VGPRs), no masks needed (OOB taps
// multiply staged/guard zeros -> bit-exact with jnp.pad).
// SROA: static indexing only. Tripwire: WRITE_SIZE ~46080 KB (round-9
// no-spill value); a jump means (256,6) forced a spill -> fall back (256,5).

#define B_ 8
#define C_ 256
#define G_ 8
#define CG_ 32
#define H_ 64
#define W_ 64
#define K2_ 25
#define HW_ (H_ * W_)
#define NCH 4
#define NROWS 20          // 16-row band + 2 halo each side
#define PITCH 70          // words per row: 2 left-guard/pad + 64 data + 4 pad
#define CHSTRIDE 1404     // 2 + 20*70 = 1402, rounded to %4==0

__global__ __launch_bounds__(256, 6) void ska_kernel(
    const float* __restrict__ x, const float* __restrict__ w,
    float* __restrict__ out) {
  __shared__ __align__(16) float lds[NCH * CHSTRIDE];  // 5616 words = 22.5 KB
  const int tid = threadIdx.x;
  const int lr = tid >> 4;   // output row within band (0..15)
  const int j = tid & 15;    // column quad (cols 4j..4j+3)
  const int wcol = j * 4;

  // blockIdx = [chunk(3) | b(3) | g(3) | band(2)], 2048 blocks
  const int blk = blockIdx.x;
  const int band = blk & 3;
  const int g = (blk >> 2) & 7;
  const int b = (blk >> 5) & 7;
  const int chunk = blk >> 8;  // 0..7

  const int h0 = band * 16;
  const int h = h0 + lr;

  // ---- weight base; issue di=0 row of weights before staging (overlap) ----
  const float* wb =
      w + (size_t)(b * G_ + g) * K2_ * HW_ + (size_t)h * W_ + wcol;
  float4 wcur0 = *(const float4*)(wb + (size_t)0 * HW_);
  float4 wcur1 = *(const float4*)(wb + (size_t)1 * HW_);
  float4 wcur2 = *(const float4*)(wb + (size_t)2 * HW_);
  float4 wcur3 = *(const float4*)(wb + (size_t)3 * HW_);
  float4 wcur4 = *(const float4*)(wb + (size_t)4 * HW_);

  // ---- zero guard/pad words ----
  // Per channel: words {0,1} (row-0 left guard) + per row r in [0,20):
  // words r*70+66..71 (right pad cols 64,65; unread 68,69; next row's left
  // guard 70,71 = (r+1)*70+{0,1}). 2 + 20*6 = 122 used; schedule 4ch x 126.
#pragma unroll
  for (int it = 0; it < 2; ++it) {
    const int i = tid + it * 256;
    if (i < 504) {
      const int c = i / 126;
      const int p = i - c * 126;
      const int r = p / 6;            // 0..20
      const int s = p - r * 6;        // 0..5
      if (r == 0) {
        if (s < 2) lds[c * CHSTRIDE + s] = 0.0f;
      } else {
        lds[c * CHSTRIDE + (r - 1) * PITCH + 66 + s] = 0.0f;
      }
    }
  }

  // ---- stage x: 20-row window x 4 channels = 1280 quads = 5*256 exact ----
  const size_t chan0 = (size_t)(b * C_ + g * CG_ + chunk * NCH) * HW_;
  const float* xc = x + chan0;
#pragma unroll
  for (int it = 0; it < 5; ++it) {
    const int i = tid + it * 256;     // 0..1279, no bounds check needed
    const int c = i / 320;            // channel 0..3 (magic mul)
    const int rem = i - c * 320;
    const int rl = rem >> 4;          // window row 0..19
    const int q = rem & 15;           // column quad
    const int gr = h0 - 2 + rl;       // global row, may be OOB
    float4 v = make_float4(0.f, 0.f, 0.f, 0.f);
    if ((unsigned)gr < (unsigned)H_)
      v = *(const float4*)(xc + (size_t)c * HW_ + gr * W_ + q * 4);
    const int wo = c * CHSTRIDE + 2 + rl * PITCH + q * 4;  // 8B aligned
    *(float2*)&lds[wo] = make_float2(v.x, v.y);
    *(float2*)&lds[wo + 2] = make_float2(v.z, v.w);
  }

  __syncthreads();

  // ---- compute: di outer (weight row double-buffer), channels inner ----
  alignas(16) float acc[NCH][4];
#pragma unroll
  for (int c = 0; c < NCH; ++c) {
    acc[c][0] = 0.f; acc[c][1] = 0.f; acc[c][2] = 0.f; acc[c][3] = 0.f;
  }

  float4 wn0, wn1, wn2, wn3, wn4;
#pragma unroll
  for (int di = 0; di < 5; ++di) {
    if (di < 4) {  // prefetch next tap-row's 5 weight quads
      const size_t kb = (size_t)((di + 1) * 5) * HW_;
      wn0 = *(const float4*)(wb + kb + 0 * HW_);
      wn1 = *(const float4*)(wb + kb + 1 * HW_);
      wn2 = *(const float4*)(wb + kb + 2 * HW_);
      wn3 = *(const float4*)(wb + kb + 3 * HW_);
      wn4 = *(const float4*)(wb + kb + 4 * HW_);
    }
    // window row (lr+di), words rbase..rbase+7 = cols wcol-2..wcol+5.
    // 4x ds_read_b64, all 8B-aligned; uniform 4 lanes/bank-pair (floor).
    const int rbase = (lr + di) * PITCH + wcol;
#pragma unroll
    for (int c = 0; c < NCH; ++c) {
      const int a = c * CHSTRIDE + rbase;
      alignas(16) float xr[8];
      *(float2*)&xr[0] = *(const float2*)&lds[a];
      *(float2*)&xr[2] = *(const float2*)&lds[a + 2];
      *(float2*)&xr[4] = *(const float2*)&lds[a + 4];
      *(float2*)&xr[6] = *(const float2*)&lds[a + 6];
#pragma unroll
      for (int dj = 0; dj < 5; ++dj) {
        const float4 wv = (dj == 0) ? wcur0
                        : (dj == 1) ? wcur1
                        : (dj == 2) ? wcur2
                        : (dj == 3) ? wcur3
                                    : wcur4;
        acc[c][0] = fmaf(xr[dj + 0], wv.x, acc[c][0]);
        acc[c][1] = fmaf(xr[dj + 1], wv.y, acc[c][1]);
        acc[c][2] = fmaf(xr[dj + 2], wv.z, acc[c][2]);
        acc[c][3] = fmaf(xr[dj + 3], wv.w, acc[c][3]);
      }
    }
    // rotate double-buffer (dead on di==4, DCE'd; full unroll renames)
    wcur0 = wn0; wcur1 = wn1; wcur2 = wn2; wcur3 = wn3; wcur4 = wn4;
  }

  float* ob = out + chan0 + (size_t)h * W_ + wcol;
#pragma unroll
  for (int c = 0; c < NCH; ++c)
    *(float4*)(ob + (size_t)c * HW_) = *(const float4*)acc[c];
}

extern "C" void kernel_launch(void* const* d_in, const int* in_sizes, int n_in,
                              void* d_out, int out_size, void* d_ws,
                              size_t ws_size, hipStream_t stream) {
  const float* x = (const float*)d_in[0];
  const float* w = (const float*)d_in[1];
  float* out = (float*)d_out;
  // grid: 8 chunks * 8 b * 8 g * 4 bands = 2048 blocks of 256 threads
  ska_kernel<<<dim3(2048), dim3(256), 0, stream>>>(x, w, out);
}

// Round 4
// 111.054 us; speedup vs baseline: 1.3072x; 1.3072x over previous
//
#include <hip/hip_runtime.h>

// SKA: per-pixel dynamic depthwise 5x5 conv
// x: [B=8, C=256, H=64, W=64] f32
// w: [B=8, G=8, K2=25, H=64, W=64] f32
// out[b,c,h,w] = sum_k x[b,c,h+k/5-2,w+k%5-2] * w[b,g,k,h,w], g = c/32
//
// Design H3 (round 11): spill fix + linear LDS + weight-side masking.
// Round-10 post-mortem: (256,6) + occupancy quantum (waves/EU steps at VGPR
// 64/128/256, m69) forced VGPR_Count=40 -> ~125MB scratch traffic (WRITE
// 46->113MB, FETCH 50->109MB), dur 50->66us. Separately, SQ_LDS_BANK_CONFLICT
// (~6 counts/b64, ~15/b128) tracks the *inherent* multi-lane bank aliasing of
// wide wave64 LDS ops (2 addr/bank is ~free per m136) -- NOT a cost signal;
// rounds 9-10's conflict chase was a phantom.
// Changes:
//  - __launch_bounds__(256,4): VGPR cap 128 (natural ~100, no spill), HW
//    occupancy 4 waves/SIMD; LDS 20.5KB -> VGPR-bound at 4 blocks/CU.
//  - Linear PITCH=64 rows, no guards/pads: staging is one float4 b128
//    write/lane (2 lanes/bank, free). Row OOB => clamp staged row; col/row
//    OOB taps are killed by weight-side cndmask (rowok/colok) at w-load,
//    exact *0.0 => bit-identical to jnp.pad. Only 16 header/slack words
//    zeroed (edge b64 reads touch them; garbage must stay finite).
//  - Keep: one __syncthreads, weight row double-buffer (40 VGPRs), chunk in
//    slow blockIdx bits (w-sharing blocks on one XCD), NCH=4, grid 2048.
// Tripwire: WRITE_SIZE ~34-40MB & VGPR ~100-120; WRITE jump or VGPR=128 =>
// spill => fall back to (256,3).

#define B_ 8
#define C_ 256
#define G_ 8
#define CG_ 32
#define H_ 64
#define W_ 64
#define K2_ 25
#define HW_ (H_ * W_)
#define NCH 4
#define NROWS 20            // 16-row band + 2 halo each side (clamped)
#define HDR 4               // header words (zeroed; left-edge reads land here)
#define CHW (NROWS * W_)    // 1280 words per channel, linear rows
#define LDSW (HDR + NCH * CHW + 12)  // 5136 words = 20.5 KB

// masked weight-quad load: D = (rowok && colok) ? w : 0
#define LDW(DI, Q) (*(const float4*)(wb + (size_t)((DI) * 5 + (Q)) * HW_))
#define MASKW(D, A, DJ, ROK)                      \
  D.x = ((ROK) && v[(DJ) + 0]) ? A.x : 0.0f;      \
  D.y = ((ROK) && v[(DJ) + 1]) ? A.y : 0.0f;      \
  D.z = ((ROK) && v[(DJ) + 2]) ? A.z : 0.0f;      \
  D.w = ((ROK) && v[(DJ) + 3]) ? A.w : 0.0f;

__global__ __launch_bounds__(256, 4) void ska_kernel(
    const float* __restrict__ x, const float* __restrict__ w,
    float* __restrict__ out) {
  __shared__ __align__(16) float lds[LDSW];
  const int tid = threadIdx.x;
  const int lr = tid >> 4;   // output row within band (0..15)
  const int j = tid & 15;    // column quad (cols 4j..4j+3)
  const int wcol = j * 4;

  // blockIdx = [chunk(3) | b(3) | g(3) | band(2)], 2048 blocks.
  // chunk slowest: blk%8 unchanged by chunk -> w-sharing partners same XCD.
  const int blk = blockIdx.x;
  const int band = blk & 3;
  const int g = (blk >> 2) & 7;
  const int b = (blk >> 5) & 7;
  const int chunk = blk >> 8;  // 0..7

  const int h0 = band * 16;
  const int h = h0 + lr;

  // col-validity for tap columns wcol-2 .. wcol+5 (only j==0 / j==15 masked)
  bool v[8];
#pragma unroll
  for (int K = 0; K < 8; ++K) v[K] = (unsigned)(wcol + K - 2) < (unsigned)W_;

  // zero header + slack words (edge reads touch them; must be finite/0)
  if (tid < 16) lds[(tid < 4) ? tid : (HDR + NCH * CHW + tid - 4)] = 0.0f;

  // ---- weight base; load+mask di=0 row before staging (latency overlap) ----
  const float* wb =
      w + (size_t)(b * G_ + g) * K2_ * HW_ + (size_t)h * W_ + wcol;
  float4 wc0, wc1, wc2, wc3, wc4;
  {
    const bool rok = (unsigned)(h - 2) < (unsigned)H_;
    const float4 a0 = LDW(0, 0), a1 = LDW(0, 1), a2 = LDW(0, 2),
                 a3 = LDW(0, 3), a4 = LDW(0, 4);
    MASKW(wc0, a0, 0, rok) MASKW(wc1, a1, 1, rok) MASKW(wc2, a2, 2, rok)
    MASKW(wc3, a3, 3, rok) MASKW(wc4, a4, 4, rok)
  }

  // ---- stage x: 20 rows x 4 channels = 1280 quads = 5*256 exact ----
  // OOB window rows are staged as clamped copies (values unused: rowok=0).
  const size_t chan0 = (size_t)(b * C_ + g * CG_ + chunk * NCH) * HW_;
  const float* xc = x + chan0;
#pragma unroll
  for (int it = 0; it < 5; ++it) {
    const int i = tid + it * 256;
    const int c = i / 320;            // magic-mul
    const int rem = i - c * 320;
    const int rl = rem >> 4;          // window row 0..19
    const int q = rem & 15;           // column quad
    int gr = h0 - 2 + rl;
    gr = min(max(gr, 0), H_ - 1);     // clamp (weight mask kills these taps)
    const float4 val =
        *(const float4*)(xc + (size_t)c * HW_ + gr * W_ + q * 4);
    *(float4*)&lds[HDR + c * CHW + rem * 4] = val;  // b128, conflict-free
  }

  __syncthreads();

  // ---- compute: di outer (weight row double-buffer), channels inner ----
  alignas(16) float acc[NCH][4];
#pragma unroll
  for (int c = 0; c < NCH; ++c) {
    acc[c][0] = 0.f; acc[c][1] = 0.f; acc[c][2] = 0.f; acc[c][3] = 0.f;
  }

  float4 wn0, wn1, wn2, wn3, wn4;
#pragma unroll
  for (int di = 0; di < 5; ++di) {
    if (di < 4) {  // prefetch + mask next tap-row (hides under FMAs)
      const bool rok = (unsigned)(h + di - 1) < (unsigned)H_;  // h+(di+1)-2
      const float4 a0 = LDW(di + 1, 0), a1 = LDW(di + 1, 1),
                   a2 = LDW(di + 1, 2), a3 = LDW(di + 1, 3),
                   a4 = LDW(di + 1, 4);
      MASKW(wn0, a0, 0, rok) MASKW(wn1, a1, 1, rok) MASKW(wn2, a2, 2, rok)
      MASKW(wn3, a3, 3, rok) MASKW(wn4, a4, 4, rok)
    }
    // window row (lr+di), words rbase..rbase+7 = cols wcol-2..wcol+5
    const int rbase = HDR + (lr + di) * W_ + wcol - 2;
#pragma unroll
    for (int c = 0; c < NCH; ++c) {
      const int a0 = rbase + c * CHW;
      alignas(16) float xr[8];
      *(float2*)&xr[0] = *(const float2*)&lds[a0];
      *(float2*)&xr[2] = *(const float2*)&lds[a0 + 2];
      *(float2*)&xr[4] = *(const float2*)&lds[a0 + 4];
      *(float2*)&xr[6] = *(const float2*)&lds[a0 + 6];
#pragma unroll
      for (int dj = 0; dj < 5; ++dj) {
        const float4 wv = (dj == 0) ? wc0
                        : (dj == 1) ? wc1
                        : (dj == 2) ? wc2
                        : (dj == 3) ? wc3
                                    : wc4;
        acc[c][0] = fmaf(xr[dj + 0], wv.x, acc[c][0]);
        acc[c][1] = fmaf(xr[dj + 1], wv.y, acc[c][1]);
        acc[c][2] = fmaf(xr[dj + 2], wv.z, acc[c][2]);
        acc[c][3] = fmaf(xr[dj + 3], wv.w, acc[c][3]);
      }
    }
    // rotate double-buffer (dead on di==4; full unroll renames)
    wc0 = wn0; wc1 = wn1; wc2 = wn2; wc3 = wn3; wc4 = wn4;
  }

  float* ob = out + chan0 + (size_t)h * W_ + wcol;
#pragma unroll
  for (int c = 0; c < NCH; ++c)
    *(float4*)(ob + (size_t)c * HW_) = *(const float4*)acc[c];
}

extern "C" void kernel_launch(void* const* d_in, const int* in_sizes, int n_in,
                              void* d_out, int out_size, void* d_ws,
                              size_t ws_size, hipStream_t stream) {
  const float* x = (const float*)d_in[0];
  const float* w = (const float*)d_in[1];
  float* out = (float*)d_out;
  // grid: 8 chunks * 8 b * 8 g * 4 bands = 2048 blocks of 256 threads
  ska_kernel<<<dim3(2048), dim3(256), 0, stream>>>(x, w, out);
}

// Round 5
// 107.707 us; speedup vs baseline: 1.3478x; 1.0311x over previous
//
#include <hip/hip_runtime.h>

// SKA: per-pixel dynamic depthwise 5x5 conv
// x: [B=8, C=256, H=64, W=64] f32
// w: [B=8, G=8, K2=25, H=64, W=64] f32
// out[b,c,h,w] = sum_k x[b,c,h+k/5-2,w+k%5-2] * w[b,g,k,h,w], g = c/32
//
// Design H4 (round 12): H3 + PITCH=66 bank fix. Single-variable change.
// Round-11 post-mortem: H3 (~36us est.) was the best yet, but its linear
// PITCH=64 rows put the wave's 4 rows on IDENTICAL banks (64 ≡ 0 mod 32):
// each ds_read_b64 has 4 rows x {j, j+8} = 8 distinct addrs/bank = 8-way
// conflict = 2.94x (m136). ~2560 wave-b64/CU x 8clk x 2.94 ≈ 25us of LDS
// pipe — the dominant term. PITCH=66 (stride ≡ 2 mod 32): collisions only
// at (dR=2, dj=-1) -> 4 addrs/bank = 1.58x. Odd pitch would be 2-way but
// breaks 8B alignment (b32 pairs at 5.8clk = net worse).
// Row/col OOB: clamp staged rows; weight-side cndmask folds OOB taps to
// exact *0.0 (bit-identical to jnp.pad). Pads/guards zeroed (168 words):
// edge b64 reads pull them into xr regs; must be finite (NaN*0=NaN).
// Keep from H3: __launch_bounds__(256,4) (VGPR cap 128, no spill; round-10's
// (256,6) forced VGPR=40 -> 125MB scratch), one __syncthreads, weight row
// double-buffer (40 VGPRs), chunk in slow blockIdx bits (w-sharing partners
// same XCD; w L2-resident after chunk round 0), NCH=4, grid 2048.
// Tripwires: VGPR ~96-112 & WRITE_SIZE ~33MB (VGPR=128 or WRITE jump =>
// spill); dur no better than H3 => conflict theory wrong -> next: NCH=8
// (halves w L2 traffic).

#define B_ 8
#define C_ 256
#define G_ 8
#define CG_ 32
#define H_ 64
#define W_ 64
#define K2_ 25
#define HW_ (H_ * W_)
#define NCH 4
#define NROWS 20            // 16-row band + 2 halo each side (clamped)
#define PITCH 66            // 64 data + 2 pad words; stride ≡ 2 mod 32 banks
#define CHSTRIDE 1322       // 2 guard words + 20*66
#define LDSW (NCH * CHSTRIDE)  // 5288 words = 21.2 KB

// word(c,r,col) = c*CHSTRIDE + 2 + r*PITCH + col ; col -2..-1 of row r land
// in row r-1's pads (r=0: channel guard words 0,1) — zeroed below.

// masked weight-quad load: D = (rowok && colok) ? w : 0
#define LDW(DI, Q) (*(const float4*)(wb + (size_t)((DI) * 5 + (Q)) * HW_))
#define MASKW(D, A, DJ, ROK)                      \
  D.x = ((ROK) && v[(DJ) + 0]) ? A.x : 0.0f;      \
  D.y = ((ROK) && v[(DJ) + 1]) ? A.y : 0.0f;      \
  D.z = ((ROK) && v[(DJ) + 2]) ? A.z : 0.0f;      \
  D.w = ((ROK) && v[(DJ) + 3]) ? A.w : 0.0f;

__global__ __launch_bounds__(256, 4) void ska_kernel(
    const float* __restrict__ x, const float* __restrict__ w,
    float* __restrict__ out) {
  __shared__ __align__(16) float lds[LDSW];
  const int tid = threadIdx.x;
  const int lr = tid >> 4;   // output row within band (0..15)
  const int j = tid & 15;    // column quad (cols 4j..4j+3)
  const int wcol = j * 4;

  // blockIdx = [chunk(3) | b(3) | g(3) | band(2)], 2048 blocks.
  // chunk slowest: blk%8 unchanged by chunk -> w-sharing partners same XCD.
  const int blk = blockIdx.x;
  const int band = blk & 3;
  const int g = (blk >> 2) & 7;
  const int b = (blk >> 5) & 7;
  const int chunk = blk >> 8;  // 0..7

  const int h0 = band * 16;
  const int h = h0 + lr;

  // col-validity for tap columns wcol-2 .. wcol+5 (only j==0 / j==15 masked)
  bool v[8];
#pragma unroll
  for (int K = 0; K < 8; ++K) v[K] = (unsigned)(wcol + K - 2) < (unsigned)W_;

  // ---- zero guards (2/ch) + row pads (2 per row) : 42 words x 4 ch ----
  if (tid < NCH * 42) {
    const int c = tid / 42;           // magic-mul
    const int p = tid - c * 42;
    const int word =
        (p < 2) ? p : (2 + ((p - 2) >> 1) * PITCH + 64 + ((p - 2) & 1));
    lds[c * CHSTRIDE + word] = 0.0f;
  }

  // ---- weight base; load+mask di=0 row before staging (latency overlap) ----
  const float* wb =
      w + (size_t)(b * G_ + g) * K2_ * HW_ + (size_t)h * W_ + wcol;
  float4 wc0, wc1, wc2, wc3, wc4;
  {
    const bool rok = (unsigned)(h - 2) < (unsigned)H_;
    const float4 a0 = LDW(0, 0), a1 = LDW(0, 1), a2 = LDW(0, 2),
                 a3 = LDW(0, 3), a4 = LDW(0, 4);
    MASKW(wc0, a0, 0, rok) MASKW(wc1, a1, 1, rok) MASKW(wc2, a2, 2, rok)
    MASKW(wc3, a3, 3, rok) MASKW(wc4, a4, 4, rok)
  }

  // ---- stage x: 20 rows x 4 channels = 1280 quads = 5*256 exact ----
  // OOB window rows staged as clamped copies (their taps get w=0).
  const size_t chan0 = (size_t)(b * C_ + g * CG_ + chunk * NCH) * HW_;
  const float* xc = x + chan0;
#pragma unroll
  for (int it = 0; it < 5; ++it) {
    const int i = tid + it * 256;
    const int c = i / 320;            // magic-mul
    const int rem = i - c * 320;
    const int rl = rem >> 4;          // window row 0..19
    const int q = rem & 15;           // column quad
    int gr = h0 - 2 + rl;
    gr = min(max(gr, 0), H_ - 1);     // clamp (weight mask kills these taps)
    const float4 val =
        *(const float4*)(xc + (size_t)c * HW_ + gr * W_ + q * 4);
    const int wo = c * CHSTRIDE + 2 + rl * PITCH + q * 4;  // 8B aligned
    *(float2*)&lds[wo] = make_float2(val.x, val.y);
    *(float2*)&lds[wo + 2] = make_float2(val.z, val.w);
  }

  __syncthreads();

  // ---- compute: di outer (weight row double-buffer), channels inner ----
  alignas(16) float acc[NCH][4];
#pragma unroll
  for (int c = 0; c < NCH; ++c) {
    acc[c][0] = 0.f; acc[c][1] = 0.f; acc[c][2] = 0.f; acc[c][3] = 0.f;
  }

  float4 wn0, wn1, wn2, wn3, wn4;
#pragma unroll
  for (int di = 0; di < 5; ++di) {
    if (di < 4) {  // prefetch + mask next tap-row (hides under FMAs)
      const bool rok = (unsigned)(h + di - 1) < (unsigned)H_;  // h+(di+1)-2
      const float4 a0 = LDW(di + 1, 0), a1 = LDW(di + 1, 1),
                   a2 = LDW(di + 1, 2), a3 = LDW(di + 1, 3),
                   a4 = LDW(di + 1, 4);
      MASKW(wn0, a0, 0, rok) MASKW(wn1, a1, 1, rok) MASKW(wn2, a2, 2, rok)
      MASKW(wn3, a3, 3, rok) MASKW(wn4, a4, 4, rok)
    }
    // window row R=lr+di, words a0..a0+7 = cols wcol-2..wcol+5
    // a0 = c*CHSTRIDE + R*66 + wcol  (== word(c,R,wcol-2); even => 8B align)
    const int rbase = (lr + di) * PITCH + wcol;
#pragma unroll
    for (int c = 0; c < NCH; ++c) {
      const int a0 = c * CHSTRIDE + rbase;
      alignas(16) float xr[8];
      *(float2*)&xr[0] = *(const float2*)&lds[a0];
      *(float2*)&xr[2] = *(const float2*)&lds[a0 + 2];
      *(float2*)&xr[4] = *(const float2*)&lds[a0 + 4];
      *(float2*)&xr[6] = *(const float2*)&lds[a0 + 6];
#pragma unroll
      for (int dj = 0; dj < 5; ++dj) {
        const float4 wv = (dj == 0) ? wc0
                        : (dj == 1) ? wc1
                        : (dj == 2) ? wc2
                        : (dj == 3) ? wc3
                                    : wc4;
        acc[c][0] = fmaf(xr[dj + 0], wv.x, acc[c][0]);
        acc[c][1] = fmaf(xr[dj + 1], wv.y, acc[c][1]);
        acc[c][2] = fmaf(xr[dj + 2], wv.z, acc[c][2]);
        acc[c][3] = fmaf(xr[dj + 3], wv.w, acc[c][3]);
      }
    }
    // rotate double-buffer (dead on di==4; full unroll renames)
    wc0 = wn0; wc1 = wn1; wc2 = wn2; wc3 = wn3; wc4 = wn4;
  }

  float* ob = out + chan0 + (size_t)h * W_ + wcol;
#pragma unroll
  for (int c = 0; c < NCH; ++c)
    *(float4*)(ob + (size_t)c * HW_) = *(const float4*)acc[c];
}

extern "C" void kernel_launch(void* const* d_in, const int* in_sizes, int n_in,
                              void* d_out, int out_size, void* d_ws,
                              size_t ws_size, hipStream_t stream) {
  const float* x = (const float*)d_in[0];
  const float* w = (const float*)d_in[1];
  float* out = (float*)d_out;
  // grid: 8 chunks * 8 b * 8 g * 4 bands = 2048 blocks of 256 threads
  ska_kernel<<<dim3(2048), dim3(256), 0, stream>>>(x, w, out);
}